// Round 2
// baseline (220.985 us; speedup 1.0000x reference)
//
#include <hip/hip_runtime.h>
#include <math.h>

typedef unsigned int u32;

#define NBINS 10
#define NE 9                 // interior edges
#define TPB 256
#define NSLOT 19             // per-block partials: 9 cum-counts + 9 cum-sums + 1 total-bce
#define CNT_BIT 25           // packed u32: count in bits [25:31], fixed-sum in [0:24]
#define FIXSCALE 4096.0f
#define SUM_MASK ((1u << CNT_BIT) - 1u)

// z-space bin edges: ZE[j] = logit((j+1)/9.9999), f32 (validated: absmax=0 in r1).
// For t in {0,1}: g = |sigmoid(x)-t| = sigmoid((1-2t)*x) = sigmoid(z),
// so (g >= (j+1)/9.9999) <=> (z >= ZE[j]).  bce = softplus(z).
//
// Packed accumulator: su[j] += (z>=ZE[j]) ? ((1<<25) | u32(bce*4096+0.5)) : 0.
// Margins (<=63 elems/thread): count <= 63 @bit25 < 2^31; sum <= 63*24.2k < 2^25.
__device__ __forceinline__ void ghm_accum4(float4 xv, float4 tv,
                                           float& s0, u32* __restrict__ su) {
    const float ZE[NE] = {
        -2.1972135f, -1.3862819f, -0.84728357f, -0.40544844f,
         2.0000200e-5f, 0.40549011f, 0.84733119f, 1.3863444f, 2.1973246f
    };
    float xs[4] = {xv.x, xv.y, xv.z, xv.w};
    float ts[4] = {tv.x, tv.y, tv.z, tv.w};
    float z[4], bce[4];
    u32 pk[4];
    #pragma unroll
    for (int k = 0; k < 4; ++k) {
        float zz = xs[k] * fmaf(ts[k], -2.0f, 1.0f);     // (1-2t)*x
        float e  = __expf(-fabsf(zz));                   // exp(-|z|)
        float b  = fmaxf(zz, 0.0f) + __logf(1.0f + e);   // softplus(z) = stable BCE
        z[k] = zz;
        bce[k] = b;
        pk[k] = ((u32)(b * FIXSCALE + 0.5f)) | (1u << CNT_BIT);
    }
    s0 += (bce[0] + bce[1]) + (bce[2] + bce[3]);         // tree -> v_add3 fusion
    #pragma unroll
    for (int j = 0; j < NE; ++j) {                       // 4 cmp + 4 cnd + ~2 add3 per edge
        u32 c0 = (z[0] >= ZE[j]) ? pk[0] : 0u;
        u32 c1 = (z[1] >= ZE[j]) ? pk[1] : 0u;
        u32 c2 = (z[2] >= ZE[j]) ? pk[2] : 0u;
        u32 c3 = (z[3] >= ZE[j]) ? pk[3] : 0u;
        su[j] += (c0 + c1) + (c2 + c3);
    }
}

// Full-wave (64-lane) DPP sum; valid result in lane 63. Zero DS ops. (validated r1)
__device__ __forceinline__ float wred_f32(float v) {
    int u;
    u = __builtin_amdgcn_update_dpp(0, __float_as_int(v), 0x111, 0xf, 0xf, false); v += __int_as_float(u);
    u = __builtin_amdgcn_update_dpp(0, __float_as_int(v), 0x112, 0xf, 0xf, false); v += __int_as_float(u);
    u = __builtin_amdgcn_update_dpp(0, __float_as_int(v), 0x114, 0xf, 0xf, false); v += __int_as_float(u);
    u = __builtin_amdgcn_update_dpp(0, __float_as_int(v), 0x118, 0xf, 0xf, false); v += __int_as_float(u);
    u = __builtin_amdgcn_update_dpp(0, __float_as_int(v), 0x142, 0xa, 0xf, false); v += __int_as_float(u);
    u = __builtin_amdgcn_update_dpp(0, __float_as_int(v), 0x143, 0xc, 0xf, false); v += __int_as_float(u);
    return v;
}

// One fused kernel. Hot loop: pure VALU + prefetched global loads (no DS, no rcp).
// (256,8): 8 blocks/CU, hard 64-VGPR cap -> no AGPR-copy inflation (r1: VGPR=28 + ~5.5cy/instr).
// Finalize runs in the last block to finish, selected by an atomic ticket mod gridDim
// (power of two): correct for arbitrary initial counter value and across graph replays.
__global__ __launch_bounds__(TPB, 8) void ghm_fused(const float4* __restrict__ x,
                                                    const float4* __restrict__ t,
                                                    float* __restrict__ parts,
                                                    u32* __restrict__ done,
                                                    float* __restrict__ out,
                                                    int n4, float n_total) {
    float s0 = 0.0f;
    u32 su[NE];
    #pragma unroll
    for (int j = 0; j < NE; ++j) su[j] = 0u;

    const int T   = gridDim.x * blockDim.x;
    const int tid = blockIdx.x * blockDim.x + threadIdx.x;

    int i = tid;
    if (i < n4) {
        float4 xa = x[i], ta = t[i];
        for (int nx = i + T; nx < n4; nx += T) {   // 1-deep prefetch: next loads in
            float4 xb = x[nx], tb = t[nx];         // flight during current compute
            ghm_accum4(xa, ta, s0, su);
            xa = xb; ta = tb;
        }
        ghm_accum4(xa, ta, s0, su);
    }

    // unpack, then wave reduce (VALU-only DPP)
    float ccnt[NE], csum[NE];
    #pragma unroll
    for (int j = 0; j < NE; ++j) {
        ccnt[j] = (float)(su[j] >> CNT_BIT);
        csum[j] = (float)(su[j] & SUM_MASK) * (1.0f / FIXSCALE);
    }
    s0 = wred_f32(s0);
    #pragma unroll
    for (int j = 0; j < NE; ++j) { ccnt[j] = wred_f32(ccnt[j]); csum[j] = wred_f32(csum[j]); }

    __shared__ float smv[4][NSLOT];
    __shared__ u32 lastFlag;
    const int lane = threadIdx.x & 63;
    const int wave = threadIdx.x >> 6;
    if (lane == 63) {
        #pragma unroll
        for (int j = 0; j < NE; ++j) { smv[wave][j] = ccnt[j]; smv[wave][NE + j] = csum[j]; }
        smv[wave][18] = s0;
    }
    __syncthreads();
    if (threadIdx.x < NSLOT) {
        float v = smv[0][threadIdx.x] + smv[1][threadIdx.x]
                + smv[2][threadIdx.x] + smv[3][threadIdx.x];
        parts[(size_t)blockIdx.x * NSLOT + threadIdx.x] = v;
    }
    __syncthreads();                       // parts stores drained (barrier implies vmcnt(0))
    if (threadIdx.x == 0) {
        __threadfence();                   // release: parts visible device-wide
        u32 old = atomicAdd(done, 1u);
        lastFlag = ((old & ((u32)gridDim.x - 1u)) == (u32)gridDim.x - 1u) ? 1u : 0u;
    }
    __syncthreads();
    if (!lastFlag) return;
    __threadfence();                       // acquire: see all blocks' parts

    // ---- last block: reduce nb x NSLOT partials, compute final scalar ----
    float aV[NSLOT];
    #pragma unroll
    for (int s = 0; s < NSLOT; ++s) aV[s] = 0.0f;
    for (int blk = threadIdx.x; blk < (int)gridDim.x; blk += TPB) {
        #pragma unroll
        for (int s = 0; s < NSLOT; ++s) aV[s] += parts[(size_t)blk * NSLOT + s];
    }
    // counts stay exact in f32: integers <= N = 2^24 throughout
    #pragma unroll
    for (int s = 0; s < NSLOT; ++s)
        for (int off = 32; off; off >>= 1) aV[s] += __shfl_down(aV[s], off, 64);

    if (lane == 0) {
        #pragma unroll
        for (int s = 0; s < NSLOT; ++s) smv[wave][s] = aV[s];
    }
    __syncthreads();
    if (threadIdx.x == 0) {
        float Ccum[NBINS + 1], Scum[NBINS + 1];
        Ccum[0] = n_total;                 // every element lands in some bin
        Scum[0] = smv[0][18] + smv[1][18] + smv[2][18] + smv[3][18];
        for (int j = 0; j < NE; ++j) {
            Ccum[j + 1] = smv[0][j] + smv[1][j] + smv[2][j] + smv[3][j];
            Scum[j + 1] = smv[0][NE + j] + smv[1][NE + j] + smv[2][NE + j] + smv[3][NE + j];
        }
        Ccum[NBINS] = Ccum[NBINS];         // Ccum[10] set below
        Ccum[NBINS] = 0.0f;                // note: Ccum[9+1]
        Scum[NBINS] = 0.0f;
        // careful: indices 0..10; edges filled 1..9, so set [10]=0 (done above)
        float ne = 0.0f;
        float cnt[NBINS], S[NBINS];
        for (int b = 0; b < NBINS; ++b) {
            cnt[b] = Ccum[b] - Ccum[b + 1];    // exact: integer f32 diff
            S[b]   = Scum[b] - Scum[b + 1];
            ne += (cnt[b] > 0.0f) ? 1.0f : 0.0f;
        }
        float tot = 0.0f;
        for (int b = 0; b < NBINS; ++b)
            tot += S[b] / fmaxf(cnt[b] * ne, 1e-4f);   // mean(w*bce) = sum_b S_b/gd_b
        out[0] = tot;
    }
}

extern "C" void kernel_launch(void* const* d_in, const int* in_sizes, int n_in,
                              void* d_out, int out_size, void* d_ws, size_t ws_size,
                              hipStream_t stream) {
    const float4* x = (const float4*)d_in[0];
    const float4* t = (const float4*)d_in[1];
    float* out = (float*)d_out;
    int n  = in_sizes[0];          // 4096*4096, divisible by 4
    int n4 = n >> 2;

    // nb must stay a power of two (atomic-ticket mod trick). 2048 = 8 blocks/CU.
    // ws proven >= 160KB in prior rounds; need = nb*76 + 4 = 155,652 B at nb=2048.
    // (overflow-safe down to nb=1024: <=64 elems/thread fits packed-u32 margins)
    int nb = 2048;
    while (nb > 1 && ws_size < (size_t)nb * NSLOT * sizeof(float) + sizeof(u32)) nb >>= 1;

    float* parts = (float*)d_ws;
    u32*   done  = (u32*)((char*)d_ws + (size_t)nb * NSLOT * sizeof(float));

    ghm_fused<<<nb, TPB, 0, stream>>>(x, t, parts, done, out, n4, (float)n);
}